// Round 3
// baseline (1014.116 us; speedup 1.0000x reference)
//
#include <hip/hip_runtime.h>

#define B_ 32
#define T_ 4096
#define CR 64
#define CS 256
#define NL 20

typedef __bf16 bf16x8 __attribute__((ext_vector_type(8)));
typedef __bf16 bf16x4v __attribute__((ext_vector_type(4)));
typedef float f32x4 __attribute__((ext_vector_type(4)));

__device__ __forceinline__ f32x4 mfma16(bf16x8 a, bf16x8 b, f32x4 c) {
  return __builtin_amdgcn_mfma_f32_16x16x32_bf16(a, b, c, 0, 0, 0);
}

// ---------------- weight pack: fp32 -> bf16, fragment-linear layouts ------
// A-frag semantics: lane l supplies A[m=l&15][k=(l>>4)*8+j].
// Wfg2: [i][mt(4)][fr(8: 0-3=f kc, 4-7=g kc)][lane(64)][8]   (K = tap*64+ci)
// Wr2:  [i][mt(4)][kc(2)][lane(64)][8]                        (K = ci)
// Ws2:  [i][tile(16)][kc(2)][lane(64)][8]                     (K = ci)
// bsS:  sum_i b_s[i][cs]
__global__ void pack_kernel(const float* __restrict__ wf, const float* __restrict__ wg,
                            const float* __restrict__ wsn, const float* __restrict__ wr,
                            const float* __restrict__ bs,
                            __bf16* __restrict__ Wfg2, __bf16* __restrict__ Wr2,
                            __bf16* __restrict__ Ws2, float* __restrict__ bsS) {
  int n = blockIdx.x * 256 + threadIdx.x;
  if (n < 327680) {
    int j = n & 7, lane = (n >> 3) & 63, fr = (n >> 9) & 7, mt = (n >> 12) & 3, i = n >> 14;
    int cs = mt * 16 + (lane & 15);
    int k = (fr & 3) * 32 + (lane >> 4) * 8 + j;
    int ci = k & 63, tap = k >> 6;  // tap0 = delayed tap (conv k=0)
    const float* src = (fr < 4) ? wf : wg;
    Wfg2[n] = (__bf16)src[((i * 64 + cs) * 64 + ci) * 2 + tap];
  } else if (n < 409600) {
    int m = n - 327680;
    int j = m & 7, lane = (m >> 3) & 63, kc = (m >> 9) & 1, mt = (m >> 10) & 3, i = m >> 12;
    int cs = mt * 16 + (lane & 15);
    int ci = kc * 32 + (lane >> 4) * 8 + j;
    Wr2[m] = (__bf16)wr[(i * 64 + cs) * 64 + ci];
  } else if (n < 737280) {
    int m = n - 409600;
    int j = m & 7, lane = (m >> 3) & 63, kc = (m >> 9) & 1, tile = (m >> 10) & 15, i = m >> 14;
    int cs = tile * 16 + (lane & 15);
    int ci = kc * 32 + (lane >> 4) * 8 + j;
    Ws2[m] = (__bf16)wsn[i * 16384 + cs * 64 + ci];
  } else if (n < 737536) {
    int cs = n - 737280;
    float s = 0.f;
    for (int i = 0; i < NL; ++i) s += bs[i * 256 + cs];
    bsS[cs] = s;
  }
}

// ---------------- input 1x1 conv: x[b][ci][t] -> h0[b][t][c] fp32 ----------
__global__ void inconv_kernel(const float* __restrict__ x, const float* __restrict__ w_in,
                              const float* __restrict__ b_in, float* __restrict__ h0) {
  __shared__ float w[64][8];
  __shared__ float bi[64];
  int tid = threadIdx.x;
  for (int k = tid; k < 512; k += 256) w[k >> 3][k & 7] = w_in[k];
  if (tid < 64) bi[tid] = b_in[tid];
  __syncthreads();
  int b = blockIdx.x >> 4;
  int t = ((blockIdx.x & 15) << 8) + tid;
  float xv[8];
#pragma unroll
  for (int ci = 0; ci < 8; ++ci) xv[ci] = x[((size_t)b * 8 + ci) * T_ + t];
  float* orow = h0 + ((size_t)b * T_ + t) * 64;
#pragma unroll
  for (int c0 = 0; c0 < 64; c0 += 4) {
    float s0 = bi[c0], s1 = bi[c0 + 1], s2 = bi[c0 + 2], s3 = bi[c0 + 3];
#pragma unroll
    for (int ci = 0; ci < 8; ++ci) {
      s0 += w[c0][ci] * xv[ci];
      s1 += w[c0 + 1][ci] * xv[ci];
      s2 += w[c0 + 2][ci] * xv[ci];
      s3 += w[c0 + 3][ci] * xv[ci];
    }
    float4 o = make_float4(s0, s1, s2, s3);
    *(float4*)(orow + c0) = o;
  }
}

// ---------------- one gated residual layer (128-t tile) -------------------
// h_in/h_out: [b][t][64] fp32.
// Zg (B-frag order): [b][tt(64)][slot][nt(4)][kc(2)][lane(64)][8] bf16,
//   element = z[t = tt*64 + nt*16 + (lane&15)][ci = kc*32 + (lane>>4)*8 + j].
__global__ __launch_bounds__(256) void layer_kernel(
    const float* __restrict__ h_in, float* __restrict__ h_out,
    const __bf16* __restrict__ Wfg, const __bf16* __restrict__ Wr,
    const float* __restrict__ bF, const float* __restrict__ bG,
    const float* __restrict__ bR,
    __bf16* __restrict__ Zg, int d, int il, int Gs) {
  __shared__ __bf16 sB[2][128][72];  // [0]=delayed tap (reused as sZ), [1]=current

  const int tid = threadIdx.x;
  const int b = blockIdx.x >> 5;
  const int tb = blockIdx.x & 31;
  const int t0 = tb << 7;
  const float* hbase = h_in + ((size_t)b * T_ + t0) * 64;

#pragma unroll
  for (int it = 0; it < 8; ++it) {
    int f = (it * 256 + tid) * 4;  // flat fp32 index into 128x64 tile
    int tr = f >> 6, c = f & 63;
    float4 v = *(const float4*)(hbase + tr * 64 + c);
    bf16x4v pc = {(__bf16)v.x, (__bf16)v.y, (__bf16)v.z, (__bf16)v.w};
    *(bf16x4v*)&sB[1][tr][c] = pc;
    int td = t0 + tr - d;
    float4 u = make_float4(0.f, 0.f, 0.f, 0.f);
    if (td >= 0) u = *(const float4*)(h_in + ((size_t)b * T_ + td) * 64 + c);
    bf16x4v pd = {(__bf16)u.x, (__bf16)u.y, (__bf16)u.z, (__bf16)u.w};
    *(bf16x4v*)&sB[0][tr][c] = pd;
  }
  __syncthreads();

  const int lane = tid & 63, wid = tid >> 6;
  const int rb = wid << 5;  // this wave's 32 time rows
  const int kq = lane >> 4;

  bf16x8 bh[2][4];  // [nt][kc]: kc0,1 = delayed tap, kc2,3 = current
#pragma unroll
  for (int nt = 0; nt < 2; ++nt) {
    int tl = rb + (nt << 4) + (lane & 15);
    bh[nt][0] = *(const bf16x8*)&sB[0][tl][kq * 8];
    bh[nt][1] = *(const bf16x8*)&sB[0][tl][32 + kq * 8];
    bh[nt][2] = *(const bf16x8*)&sB[1][tl][kq * 8];
    bh[nt][3] = *(const bf16x8*)&sB[1][tl][32 + kq * 8];
  }

  __bf16 (*sZ)[72] = sB[0];  // overlay: wave-private rows (read own frags first)

#pragma unroll
  for (int mt = 0; mt < 4; ++mt) {
    const __bf16* wb = Wfg + (mt * 8) * 512 + lane * 8;
    f32x4 aF[2] = {{0.f, 0.f, 0.f, 0.f}, {0.f, 0.f, 0.f, 0.f}};
    f32x4 aG[2] = {{0.f, 0.f, 0.f, 0.f}, {0.f, 0.f, 0.f, 0.f}};
#pragma unroll
    for (int kc = 0; kc < 4; ++kc) {
      bf16x8 af = *(const bf16x8*)(wb + kc * 512);
      bf16x8 ag = *(const bf16x8*)(wb + (4 + kc) * 512);
#pragma unroll
      for (int nt = 0; nt < 2; ++nt) {
        aF[nt] = mfma16(af, bh[nt][kc], aF[nt]);
        aG[nt] = mfma16(ag, bh[nt][kc], aG[nt]);
      }
    }
    const int c0 = (mt << 4) + (kq << 2);
    float4 bfv = *(const float4*)(bF + c0);
    float4 bgv = *(const float4*)(bG + c0);
    float fb[4] = {bfv.x, bfv.y, bfv.z, bfv.w};
    float gb[4] = {bgv.x, bgv.y, bgv.z, bgv.w};
#pragma unroll
    for (int nt = 0; nt < 2; ++nt) {
      bf16x4v zv;
#pragma unroll
      for (int r = 0; r < 4; ++r) {
        float fp = aF[nt][r] + fb[r];
        float gp = aG[nt][r] + gb[r];
        float e = __expf(2.f * fp);
        float th = 1.f - 2.f / (e + 1.f);      // tanh, inf-safe
        float sg = 1.f / (1.f + __expf(-gp));  // sigmoid
        zv[r] = (__bf16)(th * sg);
      }
      *(bf16x4v*)&sZ[rb + (nt << 4) + (lane & 15)][c0] = zv;
    }
  }

  // residual GEMM: wave-private rows of sZ
  bf16x8 bz[2][2];
#pragma unroll
  for (int nt = 0; nt < 2; ++nt) {
    int tl = rb + (nt << 4) + (lane & 15);
    bz[nt][0] = *(const bf16x8*)&sZ[tl][kq * 8];
    bz[nt][1] = *(const bf16x8*)&sZ[tl][32 + kq * 8];
  }
#pragma unroll
  for (int mt = 0; mt < 4; ++mt) {
    const __bf16* wrb = Wr + (mt * 2) * 512 + lane * 8;
    bf16x8 ar0 = *(const bf16x8*)(wrb);
    bf16x8 ar1 = *(const bf16x8*)(wrb + 512);
    const int c0 = (mt << 4) + (kq << 2);
    float4 brv = *(const float4*)(bR + c0);
#pragma unroll
    for (int nt = 0; nt < 2; ++nt) {
      f32x4 aR = {0.f, 0.f, 0.f, 0.f};
      aR = mfma16(ar0, bz[nt][0], aR);
      aR = mfma16(ar1, bz[nt][1], aR);
      const int tl = rb + (nt << 4) + (lane & 15);
      const float* hrow = h_in + ((size_t)b * T_ + t0 + tl) * 64 + c0;  // L1-hot
      float4 hv = *(const float4*)hrow;
      float4 o;
      o.x = hv.x + aR[0] + brv.x;
      o.y = hv.y + aR[1] + brv.y;
      o.z = hv.z + aR[2] + brv.z;
      o.w = hv.w + aR[3] + brv.w;
      *(float4*)(h_out + ((size_t)b * T_ + t0 + tl) * 64 + c0) = o;
    }
  }

  __syncthreads();
  // Z writeout in B-frag order: fully coalesced 16B/thread x4
#pragma unroll
  for (int q = 0; q < 4; ++q) {
    int g = q * 256 + tid;          // chunk of 8 elems; 1024 chunks total
    int sub = g >> 9, cc = g & 511; // sub-tile (64 t) and chunk within it
    int nt2 = cc >> 7, kc2 = (cc >> 6) & 1, ln = cc & 63;
    int row = sub * 64 + nt2 * 16 + (ln & 15);
    int col = kc2 * 32 + (ln >> 4) * 8;
    uint4 v = *(const uint4*)&sZ[row][col];
    __bf16* dst = Zg + (((size_t)(b * 64 + tb * 2 + sub)) * Gs + il) * 4096 + cc * 8;
    *(uint4*)dst = v;
  }
}

// ---------------- grouped skip GEMM: out[b][cs][t] (+)= Z . Ws^T ----------
// LDS-free: A and B fragments are contiguous 1KB wave loads from global.
__global__ __launch_bounds__(256) void skip_kernel(
    const __bf16* __restrict__ Zg, const __bf16* __restrict__ Ws2,
    const float* __restrict__ bsS, float* __restrict__ out,
    int i0, int cnt, int Gs, int first) {
  const int tid = threadIdx.x;
  const int b = blockIdx.x >> 6;
  const int tt = blockIdx.x & 63;
  const int t0 = tt << 6;
  const int lane = tid & 63, wid = tid >> 6;
  const int kq = lane >> 4;

  const __bf16* zb = Zg + ((size_t)(b * 64 + tt) * Gs) * 4096 + lane * 8;
  const __bf16* wb = Ws2 + (size_t)i0 * 16384 + (size_t)(wid * 8) * 512 + lane * 8;

  f32x4 acc[16];
#pragma unroll
  for (int q = 0; q < 16; ++q) acc[q] = (f32x4){0.f, 0.f, 0.f, 0.f};

  bf16x8 bz[8], aw[8];
#pragma unroll
  for (int f = 0; f < 8; ++f) {
    bz[f] = *(const bf16x8*)(zb + f * 512);
    aw[f] = *(const bf16x8*)(wb + f * 512);
  }

  for (int il = 0; il < cnt; ++il) {
    bf16x8 bzn[8], awn[8];
    const bool more = (il + 1) < cnt;
    if (more) {
      const __bf16* zb2 = zb + (size_t)(il + 1) * 4096;
      const __bf16* wb2 = wb + (size_t)(il + 1) * 16384;
#pragma unroll
      for (int f = 0; f < 8; ++f) {
        bzn[f] = *(const bf16x8*)(zb2 + f * 512);
        awn[f] = *(const bf16x8*)(wb2 + f * 512);
      }
    }
#pragma unroll
    for (int mt = 0; mt < 4; ++mt) {
#pragma unroll
      for (int nt = 0; nt < 4; ++nt) {
        acc[mt * 4 + nt] = mfma16(aw[mt * 2], bz[nt * 2], acc[mt * 4 + nt]);
        acc[mt * 4 + nt] = mfma16(aw[mt * 2 + 1], bz[nt * 2 + 1], acc[mt * 4 + nt]);
      }
    }
    if (more) {
#pragma unroll
      for (int f = 0; f < 8; ++f) {
        bz[f] = bzn[f];
        aw[f] = awn[f];
      }
    }
  }

  const int csb = wid * 64 + (kq << 2);
  const int tcol = t0 + (lane & 15);
#pragma unroll
  for (int mt = 0; mt < 4; ++mt) {
#pragma unroll
    for (int nt = 0; nt < 4; ++nt) {
#pragma unroll
      for (int r = 0; r < 4; ++r) {
        int cs = csb + mt * 16 + r;
        size_t idx = ((size_t)b * CS + cs) * T_ + tcol + nt * 16;
        float v = acc[mt * 4 + nt][r];
        if (first) out[idx] = v + bsS[cs];
        else out[idx] += v;
      }
    }
  }
}

extern "C" void kernel_launch(void* const* d_in, const int* in_sizes, int n_in,
                              void* d_out, int out_size, void* d_ws, size_t ws_size,
                              hipStream_t stream) {
  (void)in_sizes; (void)n_in; (void)out_size;
  const float* x    = (const float*)d_in[0];
  const float* w_in = (const float*)d_in[1];
  const float* b_in = (const float*)d_in[2];
  const float* w_f  = (const float*)d_in[3];
  const float* b_f  = (const float*)d_in[4];
  const float* w_g  = (const float*)d_in[5];
  const float* b_g  = (const float*)d_in[6];
  const float* w_s  = (const float*)d_in[7];
  const float* b_s  = (const float*)d_in[8];
  const float* w_r  = (const float*)d_in[9];
  const float* b_r  = (const float*)d_in[10];
  float* out = (float*)d_out;

  char* ws = (char*)d_ws;
  size_t off = 0;
  auto alloc = [&](size_t bytes) -> char* {
    char* p = ws + off;
    off = (off + bytes + 255) & ~(size_t)255;
    return p;
  };
  float* hA = (float*)alloc((size_t)B_ * T_ * 64 * 4);      // 32 MB
  float* hB = (float*)alloc((size_t)B_ * T_ * 64 * 4);      // 32 MB
  __bf16* Wfg2 = (__bf16*)alloc((size_t)NL * 16384 * 2);
  __bf16* Wr2  = (__bf16*)alloc((size_t)NL * 4096 * 2);
  __bf16* Ws2  = (__bf16*)alloc((size_t)NL * 16384 * 2);
  float* bsS = (float*)alloc(CS * 4);

  size_t zslot = (size_t)B_ * T_ * 64 * 2;  // 16 MB per layer slot
  size_t rem = (ws_size > off) ? (ws_size - off) : 0;
  int G = (int)(rem / zslot);
  if (G > NL) G = NL;
  if (G < 1) G = 1;
  __bf16* Zg = (__bf16*)(ws + off);

  hipLaunchKernelGGL(pack_kernel, dim3(2881), dim3(256), 0, stream,
                     w_f, w_g, w_s, w_r, b_s, Wfg2, Wr2, Ws2, bsS);
  hipLaunchKernelGGL(inconv_kernel, dim3(512), dim3(256), 0, stream, x, w_in, b_in, hA);

  float* hc = hA;
  float* hn = hB;
  int i0 = 0;
  for (int i = 0; i < NL; ++i) {
    int il = i - i0;
    hipLaunchKernelGGL(layer_kernel, dim3(B_ * 32), dim3(256), 0, stream,
                       hc, hn, Wfg2 + (size_t)i * 16384, Wr2 + (size_t)i * 4096,
                       b_f + i * 64, b_g + i * 64, b_r + i * 64,
                       Zg, 1 << (i % 10), il, G);
    { float* tmp = hc; hc = hn; hn = tmp; }
    if (il + 1 == G || i == NL - 1) {
      int cnt = il + 1;
      hipLaunchKernelGGL(skip_kernel, dim3(B_ * 64), dim3(256), 0, stream,
                         Zg, Ws2, bsS, out, i0, cnt, G, (i0 == 0) ? 1 : 0);
      i0 = i + 1;
    }
  }
}